// Round 5
// baseline (466.256 us; speedup 1.0000x reference)
//
#include <hip/hip_runtime.h>

typedef unsigned int u32;
typedef signed char  i8;

#define BM 256
#define BN 256
#define BK 64
#define NBUF 3
#define BUFSZ 16384   /* A-only per K-tile: 256 rows x 64 B */

typedef __attribute__((ext_vector_type(4))) int   i32x4;
typedef __attribute__((ext_vector_type(4))) float f4v;
typedef __attribute__((ext_vector_type(4))) u32   u4v;

// ============================================================
// Fused quantizer, one dispatch.
// Round 5: x-part restructured wave-per-row (no LDS, no syncthreads —
// the old form was 8192 tiny blocks x 2 barriers, latency-bound shape).
//   blocks [0, xblocks)      : 4 rows/block, one wave per row.
//   blocks [xblocks, total)  : sign(w) -> int8 (UNCHANGED — control)
// ============================================================
__global__ void __launch_bounds__(256) quant_fused(
    const f4v* __restrict__ x, const f4v* __restrict__ w,
    i8* __restrict__ xq, i8* __restrict__ wq, float* __restrict__ s,
    int K, int xblocks)
{
    const int t    = threadIdx.x;
    const int lane = t & 63;
    const int wave = t >> 6;

    if ((int)blockIdx.x < xblocks) {
        const int row = blockIdx.x * 4 + wave;           // one wave = one row
        const f4v* xr = x + (size_t)row * (K >> 2);
        f4v v[16];                                        // 64 floats/lane
        float amax = 0.f;
#pragma unroll
        for (int c = 0; c < 16; ++c) {
            v[c] = xr[lane * 16 + c];
            amax = fmaxf(amax, fmaxf(fmaxf(fabsf(v[c].x), fabsf(v[c].y)),
                                     fmaxf(fabsf(v[c].z), fabsf(v[c].w))));
        }
#pragma unroll
        for (int off = 32; off > 0; off >>= 1)
            amax = fmaxf(amax, __shfl_xor(amax, off));    // all lanes get max

        const float inv = (amax > 0.f) ? (127.0f / amax) : 0.f;
        if (lane == 0) s[row] = amax * (1.0f / 127.0f);

        i8* xo = xq + (size_t)row * K + lane * 64;        // 64 consecutive i8
#pragma unroll
        for (int g = 0; g < 4; ++g) {
            u4v r;
#pragma unroll
            for (int j = 0; j < 4; ++j) {
                const f4v a = v[g * 4 + j];
                int q0 = __float2int_rn(a.x * inv);
                int q1 = __float2int_rn(a.y * inv);
                int q2 = __float2int_rn(a.z * inv);
                int q3 = __float2int_rn(a.w * inv);
                r[j] = (q0 & 0xFF) | ((q1 & 0xFF) << 8) |
                       ((q2 & 0xFF) << 16) | ((u32)(q3 & 0xFF) << 24);
            }
            *(u4v*)&xo[g * 16] = r;
        }
    } else {
        const int b = blockIdx.x - xblocks;
        const f4v* wb = w + (size_t)b * 1024;
        u32* wo = (u32*)(wq + (size_t)b * 4096);
#pragma unroll
        for (int c = 0; c < 4; ++c) {
            const int idx = t + c * 256;
            f4v a = __builtin_nontemporal_load(&wb[idx]);
            u32 b0 = (a.x > 0.f) ? 1u : ((a.x < 0.f) ? 0xFFu : 0u);
            u32 b1 = (a.y > 0.f) ? 1u : ((a.y < 0.f) ? 0xFFu : 0u);
            u32 b2 = (a.z > 0.f) ? 1u : ((a.z < 0.f) ? 0xFFu : 0u);
            u32 b3 = (a.w > 0.f) ? 1u : ((a.w < 0.f) ? 0xFFu : 0u);
            wo[idx] = b0 | (b1 << 8) | (b2 << 16) | (b3 << 24);
        }
    }
}

// async 16B global -> LDS (LDS dest is wave-uniform base + lane*16)
__device__ __forceinline__ void async_cp16(const void* gp, void* lp) {
    __builtin_amdgcn_global_load_lds(
        (__attribute__((address_space(1))) void*)(gp),
        (__attribute__((address_space(3))) void*)(lp),
        16, 0, 0);
}

#define FENCE() asm volatile("" ::: "memory")

// ============================================================
// C[M,N] = (xq . wq^T) * s[row] + bias[col]  -- i8 MFMA, i32 acc
//
// Round 5: B fragments load DIRECT global->VGPR (no LDS for B).
// Model from r4 counters: LDS port (reads 96x12 + staging writes ~= 1450
// cyc/K-tile) ~= MFMA pipe (1307) and barrier lockstep serialized them
// (measured 2945 cyc/tile). LDS reads were 3x-amplified by cross-wave
// fragment redundancy. Moving B to per-wave global_load_dwordx4 puts its
// traffic on the idle VMEM pipe (8-20% busy) with COMPILER-tracked vmcnt
// waits (register deps), and cuts the LDS port to A-only (~900 cyc <
// MFMA 1307). B lane pattern: 16 rows x 64B = full lines, zero waste;
// B panels (16 MB total) are L2-resident.
// Skeleton unchanged from r4 (passed): 3-slot A rotation, stage issued
// only AFTER a barrier (cross-wave overwrite safety), counted
// vmcnt(6) = stageA(t+2)x2 + bfglobal(t+1)x4 per wave, never 0 mid-loop,
// reg ping-pong with static indices, setprio around MFMA clusters.
// A swizzle identical to r3/r4 (measured 0 conflicts).
// ============================================================
__global__ void __launch_bounds__(512, 2) gemm_i8_bt(
    const i8* __restrict__ A, const i8* __restrict__ B,
    const float* __restrict__ s, const float* __restrict__ bias,
    float* __restrict__ C, int M, int N, int K)
{
    __shared__ i8 lds[NBUF * BUFSZ];   // 48 KB, A tiles only

    const int t    = threadIdx.x;
    const int lane = t & 63;
    const int wave = t >> 6;
    const int wm   = (wave >> 2) * 128;   // 2 waves in M, 128 rows each
    const int wn   = (wave & 3) * 64;     // 4 waves in N, 64 cols each
    const int l15  = lane & 15;
    const int quad = lane >> 4;

    // XCD-aware decode: 512 blocks, xcd = bid&7, 8x8 patch per XCD (bijective)
    const int nbm = M / BM, nbn = N / BN;
    int mb, nb;
    const int bid = blockIdx.x;
    if (nbm == 32 && nbn == 16) {
        const int xcd   = bid & 7;
        const int local = bid >> 3;            // 64 blocks per XCD
        mb = ((xcd >> 1) << 3) + (local >> 3);
        nb = ((xcd & 1) << 3) + (local & 7);
    } else {
        mb = bid / nbn;
        nb = bid - mb * nbn;
    }
    const size_t m_block = (size_t)mb * BM;
    const size_t n_block = (size_t)nb * BN;

    i32x4 acc[8][4];
#pragma unroll
    for (int i = 0; i < 8; ++i)
#pragma unroll
        for (int j = 0; j < 4; ++j)
            acc[i][j] = (i32x4){0, 0, 0, 0};

    // A reader LDS byte base (paired-row swizzle, 0-conflict measured):
    // fragment (row r, chunk quad): byte=(r>>1)*128+((((r&1)<<2)|quad)^((r>>1)&7))*16
    const int slot = ((((l15 & 1) << 2) | quad) ^ ((l15 >> 1) & 7));
    const u32 aoff = (u32)(wm * 64 + (l15 >> 1) * 128 + slot * 16);

    // A staging map (inverse swizzle on the global side):
    // LDS chunk c: line=c>>3, sl=c&7, l=sl^(line&7), r=line*2+(l>>2), q=l&3
    const i8* Abase = A + m_block * K;
    u32 goff[2], lofs[2];
#pragma unroll
    for (int sidx = 0; sidx < 2; ++sidx) {
        const int c    = t + sidx * 512;
        const int line = c >> 3;
        const int sl   = c & 7;
        const int l    = sl ^ (line & 7);
        const int r    = line * 2 + (l >> 2);
        const int q    = l & 3;
        goff[sidx] = (u32)(r * K + q * 16);
        lofs[sidx] = (u32)c * 16u;
    }

    // B per-lane global base pointers: row = n_block+wn+nj*16+l15, k-chunk quad
    const i8* bptr[4];
#pragma unroll
    for (int nj = 0; nj < 4; ++nj)
        bptr[nj] = B + (size_t)(n_block + wn + nj * 16 + l15) * K + quad * 16;

    const int NT = K / BK;   // 64

#define STAGE_A(buf, kofs)                                                   \
    do {                                                                     \
        i8* lb = lds + (buf) * BUFSZ;                                        \
        async_cp16(Abase + goff[0] + (kofs), lb + lofs[0]);                  \
        async_cp16(Abase + goff[1] + (kofs), lb + lofs[1]);                  \
    } while (0)

    i32x4 a47[4];
    i32x4 af0[4], bf0[4];   // fragment set 0 (even tiles)
    i32x4 af1[4], bf1[4];   // fragment set 1 (odd tiles)

// P0(t): read a47(t) | barrier | stageA(t+2) | issue bf-global(t+1)
//        | MFMA af03(t) x bf(t)
#define PHASE0(T, AFc, BFc, BFn, DO_STAGE, DO_BF)                            \
    do {                                                                     \
        const i8* bufc_ = lds + ((T) % 3) * BUFSZ;                           \
        _Pragma("unroll")                                                    \
        for (int mi = 0; mi < 4; ++mi)                                       \
            a47[mi] = *(const i32x4*)&bufc_[aoff + (mi + 4) * 1024];         \
        __builtin_amdgcn_sched_barrier(0);                                   \
        FENCE(); __builtin_amdgcn_s_barrier(); FENCE();                      \
        if (DO_STAGE) STAGE_A(((T) + 2) % 3, ((T) + 2) * BK);                \
        if (DO_BF) {                                                         \
            _Pragma("unroll")                                                \
            for (int nj = 0; nj < 4; ++nj)                                   \
                BFn[nj] = *(const i32x4*)(bptr[nj] + ((T) + 1) * BK);        \
        }                                                                    \
        __builtin_amdgcn_sched_barrier(0);                                   \
        __builtin_amdgcn_s_setprio(1);                                       \
        _Pragma("unroll")                                                    \
        for (int mi = 0; mi < 4; ++mi)                                       \
            _Pragma("unroll")                                                \
            for (int nj = 0; nj < 4; ++nj)                                   \
                acc[mi][nj] = __builtin_amdgcn_mfma_i32_16x16x64_i8(         \
                    AFc[mi], BFc[nj], acc[mi][nj], 0, 0, 0);                 \
        __builtin_amdgcn_s_setprio(0);                                       \
        __builtin_amdgcn_sched_barrier(0);                                   \
    } while (0)

// P1(t): counted vmcnt | barrier | read af03(t+1) | MFMA a47(t) x bf(t)
#define PHASE1(T, BFc, AFn, VMN, DO_RD)                                      \
    do {                                                                     \
        if ((VMN) == 6)      asm volatile("s_waitcnt vmcnt(6)" ::: "memory");\
        else if ((VMN) == 4) asm volatile("s_waitcnt vmcnt(4)" ::: "memory");\
        else                 asm volatile("s_waitcnt vmcnt(0)" ::: "memory");\
        FENCE(); __builtin_amdgcn_s_barrier(); FENCE();                      \
        if (DO_RD) {                                                         \
            const i8* bufn_ = lds + (((T) + 1) % 3) * BUFSZ;                 \
            _Pragma("unroll")                                                \
            for (int mi = 0; mi < 4; ++mi)                                   \
                AFn[mi] = *(const i32x4*)&bufn_[aoff + mi * 1024];           \
        }                                                                    \
        __builtin_amdgcn_sched_barrier(0);                                   \
        __builtin_amdgcn_s_setprio(1);                                       \
        _Pragma("unroll")                                                    \
        for (int mi = 0; mi < 4; ++mi)                                       \
            _Pragma("unroll")                                                \
            for (int nj = 0; nj < 4; ++nj)                                   \
                acc[mi + 4][nj] = __builtin_amdgcn_mfma_i32_16x16x64_i8(     \
                    a47[mi], BFc[nj], acc[mi + 4][nj], 0, 0, 0);             \
        __builtin_amdgcn_s_setprio(0);                                       \
        __builtin_amdgcn_sched_barrier(0);                                   \
    } while (0)

    // prologue: stage A tiles 0,1 (4 vm); load bf(0) global (4 vm);
    // vmcnt(6) drains stageA(0) only; then read af03(0).
    STAGE_A(0, 0);
    STAGE_A(1, BK);
#pragma unroll
    for (int nj = 0; nj < 4; ++nj)
        bf0[nj] = *(const i32x4*)(bptr[nj]);
    asm volatile("s_waitcnt vmcnt(6)" ::: "memory");
    FENCE(); __builtin_amdgcn_s_barrier(); FENCE();
    {
        const i8* buf0_ = lds;
#pragma unroll
        for (int mi = 0; mi < 4; ++mi)
            af0[mi] = *(const i32x4*)&buf0_[aoff + mi * 1024];
    }

    // main loop: pairs (even,odd), stage while t+2 <= NT-1
    for (int tt = 0; tt + 2 < NT; tt += 2) {
        PHASE0(tt,     af0, bf0, bf1, true, true);
        PHASE1(tt,     bf0, af1, 6, true);
        PHASE0(tt + 1, af1, bf1, bf0, true, true);
        PHASE1(tt + 1, bf1, af0, 6, true);
    }
    // t = NT-2 (even, set0): no stage; load bf(NT-1); vmcnt(4) leaves it flying
    PHASE0(NT - 2, af0, bf0, bf1, false, true);
    PHASE1(NT - 2, bf0, af1, 4, true);
    // t = NT-1 (set1): final tile
    PHASE0(NT - 1, af1, bf1, bf0, false, false);
    PHASE1(NT - 1, bf1, af0, 0, false);

#undef PHASE0
#undef PHASE1
#undef STAGE_A

    // epilogue: C/D layout col=lane&15, row=quad*4+reg (dtype-independent)
    float bv[4];
#pragma unroll
    for (int nj = 0; nj < 4; ++nj)
        bv[nj] = bias[n_block + wn + nj * 16 + l15];

#pragma unroll
    for (int mi = 0; mi < 8; ++mi) {
        const size_t row0 = m_block + wm + mi * 16 + quad * 4;
        const f4v sv = *(const f4v*)&s[row0];
#pragma unroll
        for (int nj = 0; nj < 4; ++nj) {
            const size_t col = n_block + wn + nj * 16 + l15;
            __builtin_nontemporal_store((float)acc[mi][nj][0] * sv.x + bv[nj], &C[(row0 + 0) * N + col]);
            __builtin_nontemporal_store((float)acc[mi][nj][1] * sv.y + bv[nj], &C[(row0 + 1) * N + col]);
            __builtin_nontemporal_store((float)acc[mi][nj][2] * sv.z + bv[nj], &C[(row0 + 2) * N + col]);
            __builtin_nontemporal_store((float)acc[mi][nj][3] * sv.w + bv[nj], &C[(row0 + 3) * N + col]);
        }
    }
}

extern "C" void kernel_launch(void* const* d_in, const int* in_sizes, int n_in,
                              void* d_out, int out_size, void* d_ws, size_t ws_size,
                              hipStream_t stream) {
    const float* x  = (const float*)d_in[0];   // [M,K]
    const float* w  = (const float*)d_in[1];   // [N,K]
    const float* bs = (const float*)d_in[2];   // [N]
    float* out = (float*)d_out;                // [M,N]

    const int N = in_sizes[2];
    const int K = in_sizes[1] / N;
    const int M = in_sizes[0] / K;

    i8*    xq = (i8*)d_ws;                          // [M,K] int8
    i8*    wq = xq + (size_t)M * K;                 // [N,K] int8 (+-1)
    float* s  = (float*)(wq + (size_t)N * K);       // [M] fp32 row scales

    const int xblocks = M / 4;                      // wave-per-row, 4 rows/block
    const int wblocks = (int)(((size_t)N * K) / (256 * 16));
    quant_fused<<<xblocks + wblocks, 256, 0, stream>>>(
        (const f4v*)x, (const f4v*)w, xq, wq, s, K, xblocks);

    const int nblocks = (M / BM) * (N / BN);   // 512
    gemm_i8_bt<<<nblocks, 512, 0, stream>>>(xq, wq, s, bs, out, M, N, K);
}